// Round 1
// baseline (932.749 us; speedup 1.0000x reference)
//
#include <hip/hip_runtime.h>

#define N_NODES 50000
#define N_EDGES 800000
#define N_GRAPHS 512
// feature dims
#define F_IN 256
#define F_H 128   // hidden / out feats per branch
#define F_CAT 256 // both branches fused side by side

// ---------------------------------------------------------------------------
// Degree count (edge counts per node, excluding self loop)
__global__ void deg_kernel(const int* __restrict__ ei, int* cnt_td, int* cnt_bu) {
    int i = blockIdx.x * blockDim.x + threadIdx.x;
    if (i >= N_EDGES) return;
    int s = ei[i];            // edge_index[0][i]
    int d = ei[N_EDGES + i];  // edge_index[1][i]
    atomicAdd(&cnt_td[d], 1); // TD conv: segment by dst
    atomicAdd(&cnt_bu[s], 1); // BU conv: segment by src
}

// ---------------------------------------------------------------------------
// Exclusive scan of counts -> row offsets; also dinv = rsqrt(cnt+1).
// One block (1024 threads) per array; blockIdx.x in {0,1}.
__global__ void scan_dinv_kernel(const int* __restrict__ cnt0, const int* __restrict__ cnt1,
                                 int* off0, int* off1, float* dinv0, float* dinv1, int n) {
    const int* cnt = blockIdx.x ? cnt1 : cnt0;
    int* off       = blockIdx.x ? off1 : off0;
    float* dinv    = blockIdx.x ? dinv1 : dinv0;
    __shared__ int s[1024];
    int tid = threadIdx.x;
    int carry = 0;
    for (int base = 0; base < n; base += 1024) {
        int i = base + tid;
        int v = (i < n) ? cnt[i] : 0;
        if (i < n) dinv[i] = rsqrtf((float)v + 1.0f);
        s[tid] = v;
        __syncthreads();
        for (int o = 1; o < 1024; o <<= 1) {
            int t = (tid >= o) ? s[tid - o] : 0;
            __syncthreads();
            s[tid] += t;
            __syncthreads();
        }
        if (i < n) off[i] = carry + s[tid] - v;  // exclusive
        carry += s[1023];
        __syncthreads();  // protect s before next chunk overwrites
    }
}

// ---------------------------------------------------------------------------
// Scatter edges into CSR buckets
__global__ void fill_kernel(const int* __restrict__ ei,
                            const int* __restrict__ off_td, int* cur_td, int* csr_td,
                            const int* __restrict__ off_bu, int* cur_bu, int* csr_bu) {
    int i = blockIdx.x * blockDim.x + threadIdx.x;
    if (i >= N_EDGES) return;
    int s = ei[i];
    int d = ei[N_EDGES + i];
    int p = atomicAdd(&cur_td[d], 1);
    csr_td[off_td[d] + p] = s;   // TD: incoming neighbors (srcs) of node d
    int q = atomicAdd(&cur_bu[s], 1);
    csr_bu[off_bu[s] + q] = d;   // BU: flipped direction
}

// ---------------------------------------------------------------------------
// SGEMM: C[M,N] = A[M,K] @ B[K,N]. BM=BN=64, BK=16, 256 thr, 4x4 microtile.
// N must be a multiple of 64, K a multiple of 16. M guarded.
__global__ __launch_bounds__(256) void sgemm(const float* __restrict__ A, int lda,
                                             const float* __restrict__ B, int ldb,
                                             float* __restrict__ C, int ldc,
                                             int M, int K) {
    __shared__ float As[16][64];
    __shared__ float Bs[16][64];
    int tid = threadIdx.x;
    int bm = blockIdx.x * 64, bn = blockIdx.y * 64;
    int tm = (tid >> 4) * 4;
    int tn = (tid & 15) * 4;
    int arow = tid >> 2, akq = (tid & 3) * 4;   // A tile: 64 rows x 16 k
    int brow = tid >> 4, bcol = (tid & 15) * 4; // B tile: 16 k x 64 cols
    float acc[4][4] = {};
    for (int k0 = 0; k0 < K; k0 += 16) {
        float4 a4 = {0.f, 0.f, 0.f, 0.f};
        int gm = bm + arow;
        if (gm < M) a4 = *(const float4*)(A + (size_t)gm * lda + k0 + akq);
        As[akq + 0][arow] = a4.x;
        As[akq + 1][arow] = a4.y;
        As[akq + 2][arow] = a4.z;
        As[akq + 3][arow] = a4.w;
        float4 b4 = *(const float4*)(B + (size_t)(k0 + brow) * ldb + bn + bcol);
        *(float4*)(&Bs[brow][bcol]) = b4;
        __syncthreads();
#pragma unroll
        for (int kk = 0; kk < 16; kk++) {
            float a[4], b[4];
#pragma unroll
            for (int i = 0; i < 4; i++) a[i] = As[kk][tm + i];
#pragma unroll
            for (int j = 0; j < 4; j++) b[j] = Bs[kk][tn + j];
#pragma unroll
            for (int i = 0; i < 4; i++)
#pragma unroll
                for (int j = 0; j < 4; j++) acc[i][j] += a[i] * b[j];
        }
        __syncthreads();
    }
#pragma unroll
    for (int i = 0; i < 4; i++) {
        int gm = bm + tm + i;
        if (gm >= M) break;
#pragma unroll
        for (int j = 0; j < 4; j++)
            C[(size_t)gm * ldc + bn + tn + j] = acc[i][j];
    }
}

// ---------------------------------------------------------------------------
// Pull aggregation: out[n, colOff+c] = sum_{src in csr row n} lin[src]*dinv[src]*dinv[n]
//                   + lin[n]*dinv[n]^2 + bias[c]; optional relu.
// grid = (N_NODES, 2 branches), block = 128
__global__ __launch_bounds__(128) void agg_kernel(
        const float* __restrict__ lin, float* __restrict__ out,
        const int* __restrict__ csr_td, const int* __restrict__ off_td,
        const int* __restrict__ cnt_td, const float* __restrict__ dinv_td,
        const int* __restrict__ csr_bu, const int* __restrict__ off_bu,
        const int* __restrict__ cnt_bu, const float* __restrict__ dinv_bu,
        const float* __restrict__ b_td, const float* __restrict__ b_bu,
        int do_relu) {
    int n = blockIdx.x;
    int br = blockIdx.y;
    const int* csr    = br ? csr_bu : csr_td;
    const int* off    = br ? off_bu : off_td;
    const int* cnt    = br ? cnt_bu : cnt_td;
    const float* dinv = br ? dinv_bu : dinv_td;
    const float* bias = br ? b_bu : b_td;
    int c = threadIdx.x;
    int colOff = br * F_H;
    float dn = dinv[n];
    float acc = lin[(size_t)n * F_CAT + colOff + c] * dn * dn;  // self loop
    int s0 = off[n], e0 = s0 + cnt[n];
    for (int k = s0; k < e0; k++) {
        int src = csr[k];
        acc += lin[(size_t)src * F_CAT + colOff + c] * (dinv[src] * dn);
    }
    acc += bias[c];
    if (do_relu) acc = fmaxf(acc, 0.f);
    out[(size_t)n * F_CAT + colOff + c] = acc;
}

// ---------------------------------------------------------------------------
// Global add pool using sorted batch (binary search per graph).
// Writes pooled in concat([bu, td]) order.
__global__ __launch_bounds__(256) void pool_kernel(const float* __restrict__ h2,
                                                   const int* __restrict__ batch,
                                                   float* __restrict__ pooled) {
    int g = blockIdx.x;
    int c = threadIdx.x;  // 0..255
    // lower_bound(batch, g)
    int lo = 0, hi = N_NODES;
    while (lo < hi) { int mid = (lo + hi) >> 1; if (batch[mid] < g) lo = mid + 1; else hi = mid; }
    int start = lo;
    lo = start; hi = N_NODES;
    while (lo < hi) { int mid = (lo + hi) >> 1; if (batch[mid] < g + 1) lo = mid + 1; else hi = mid; }
    int end = lo;
    // concat is [bu, td]: cols 0..127 of pooled <- h2 cols 128..255 (bu half)
    int srcCol = (c < F_H) ? (F_H + c) : (c - F_H);
    float acc = 0.f;
    for (int n = start; n < end; n++) acc += h2[(size_t)n * F_CAT + srcCol];
    pooled[(size_t)g * F_CAT + c] = acc;
}

// ---------------------------------------------------------------------------
// Projection head: relu(h@pw1+pb1)@pw2+pb2. One block per graph.
__global__ __launch_bounds__(256) void mlp_kernel(const float* __restrict__ pooled,
                                                  const float* __restrict__ pw1,
                                                  const float* __restrict__ pb1,
                                                  const float* __restrict__ pw2,
                                                  const float* __restrict__ pb2,
                                                  float* __restrict__ out) {
    int g = blockIdx.x;
    int tid = threadIdx.x;
    __shared__ float row[256];
    __shared__ float hid[256];
    row[tid] = pooled[(size_t)g * 256 + tid];
    __syncthreads();
    float acc = pb1[tid];
    for (int k = 0; k < 256; k++) acc += row[k] * pw1[(size_t)k * 256 + tid];
    hid[tid] = fmaxf(acc, 0.f);
    __syncthreads();
    if (tid < 128) {
        float o = pb2[tid];
        for (int k = 0; k < 256; k++) o += hid[k] * pw2[(size_t)k * 128 + tid];
        out[(size_t)g * 128 + tid] = o;
    }
}

// ---------------------------------------------------------------------------
extern "C" void kernel_launch(void* const* d_in, const int* in_sizes, int n_in,
                              void* d_out, int out_size, void* d_ws, size_t ws_size,
                              hipStream_t stream) {
    const float* x     = (const float*)d_in[0];
    const int*   ei    = (const int*)d_in[1];
    const int*   batch = (const int*)d_in[2];
    // d_in[3] = num_graphs (512), constant
    const float* td_W1 = (const float*)d_in[4];
    const float* td_b1 = (const float*)d_in[5];
    const float* td_W2 = (const float*)d_in[6];
    const float* td_b2 = (const float*)d_in[7];
    const float* bu_W1 = (const float*)d_in[8];
    const float* bu_b1 = (const float*)d_in[9];
    const float* bu_W2 = (const float*)d_in[10];
    const float* bu_b2 = (const float*)d_in[11];
    const float* pw1   = (const float*)d_in[12];
    const float* pb1   = (const float*)d_in[13];
    const float* pw2   = (const float*)d_in[14];
    const float* pb2   = (const float*)d_in[15];
    float* out = (float*)d_out;

    // ---- workspace carve ----
    char* p = (char*)d_ws;
    auto alloc = [&](size_t bytes) { void* r = (void*)p; p += (bytes + 255) & ~(size_t)255; return r; };
    // zeroed region (one memset): cnt_td | cnt_bu | cur_td | cur_bu
    int* zero_region = (int*)alloc((size_t)4 * N_NODES * sizeof(int));
    int* cnt_td = zero_region;
    int* cnt_bu = zero_region + N_NODES;
    int* cur_td = zero_region + 2 * N_NODES;
    int* cur_bu = zero_region + 3 * N_NODES;
    int* off_td = (int*)alloc((size_t)N_NODES * sizeof(int));
    int* off_bu = (int*)alloc((size_t)N_NODES * sizeof(int));
    float* dinv_td = (float*)alloc((size_t)N_NODES * sizeof(float));
    float* dinv_bu = (float*)alloc((size_t)N_NODES * sizeof(float));
    int* csr_td = (int*)alloc((size_t)N_EDGES * sizeof(int));
    int* csr_bu = (int*)alloc((size_t)N_EDGES * sizeof(int));
    float* buf0 = (float*)alloc((size_t)N_NODES * F_CAT * sizeof(float)); // lin / lin2
    float* buf1 = (float*)alloc((size_t)N_NODES * F_CAT * sizeof(float)); // h1 / agg2
    float* pooled = (float*)alloc((size_t)N_GRAPHS * F_CAT * sizeof(float));

    hipMemsetAsync(zero_region, 0, (size_t)4 * N_NODES * sizeof(int), stream);

    // ---- graph structure ----
    deg_kernel<<<(N_EDGES + 255) / 256, 256, 0, stream>>>(ei, cnt_td, cnt_bu);
    scan_dinv_kernel<<<2, 1024, 0, stream>>>(cnt_td, cnt_bu, off_td, off_bu,
                                             dinv_td, dinv_bu, N_NODES);
    fill_kernel<<<(N_EDGES + 255) / 256, 256, 0, stream>>>(ei, off_td, cur_td, csr_td,
                                                           off_bu, cur_bu, csr_bu);

    // ---- layer 1: lin = x @ [td_W1 | bu_W1]  (N x 256) ----
    dim3 g1((N_NODES + 63) / 64, F_H / 64);
    sgemm<<<g1, 256, 0, stream>>>(x, F_IN, td_W1, F_H, buf0, F_CAT, N_NODES, F_IN);
    sgemm<<<g1, 256, 0, stream>>>(x, F_IN, bu_W1, F_H, buf0 + F_H, F_CAT, N_NODES, F_IN);
    // aggregate + bias + relu -> buf1 (h1)
    agg_kernel<<<dim3(N_NODES, 2), 128, 0, stream>>>(buf0, buf1,
        csr_td, off_td, cnt_td, dinv_td, csr_bu, off_bu, cnt_bu, dinv_bu,
        td_b1, bu_b1, /*relu=*/1);

    // ---- layer 2: lin2 = h1 @ blockdiag(td_W2, bu_W2) ----
    sgemm<<<g1, 256, 0, stream>>>(buf1, F_CAT, td_W2, F_H, buf0, F_CAT, N_NODES, F_H);
    sgemm<<<g1, 256, 0, stream>>>(buf1 + F_H, F_CAT, bu_W2, F_H, buf0 + F_H, F_CAT, N_NODES, F_H);
    // aggregate + bias (no relu) -> buf1 (h2)
    agg_kernel<<<dim3(N_NODES, 2), 128, 0, stream>>>(buf0, buf1,
        csr_td, off_td, cnt_td, dinv_td, csr_bu, off_bu, cnt_bu, dinv_bu,
        td_b2, bu_b2, /*relu=*/0);

    // ---- pool (sorted batch, binary search) ----
    pool_kernel<<<N_GRAPHS, 256, 0, stream>>>(buf1, batch, pooled);

    // ---- projection head ----
    mlp_kernel<<<N_GRAPHS, 256, 0, stream>>>(pooled, pw1, pb1, pw2, pb2, out);
}

// Round 2
// 671.366 us; speedup vs baseline: 1.3893x; 1.3893x over previous
//
#include <hip/hip_runtime.h>

#define N_NODES 50000
#define N_EDGES 800000
#define N_GRAPHS 512
#define F_IN 256
#define F_H 128   // per-branch feats
#define F_CAT 256 // both branches side by side

typedef __attribute__((ext_vector_type(8))) short short8;
typedef __attribute__((ext_vector_type(4))) float f32x4;
typedef unsigned int uint;
typedef unsigned short ushort;

static __device__ __forceinline__ ushort f2bf(float f) {
    uint u = __float_as_uint(f);
    u += 0x7FFF + ((u >> 16) & 1);  // RNE
    return (ushort)(u >> 16);
}
static __device__ __forceinline__ float bflo(uint v) { return __uint_as_float(v << 16); }
static __device__ __forceinline__ float bfhi(uint v) { return __uint_as_float(v & 0xFFFF0000u); }

// ---------------------------------------------------------------------------
// Degree count (edge counts per node, excluding self loop)
__global__ void deg_kernel(const int* __restrict__ ei, int* cnt_td, int* cnt_bu) {
    int i = blockIdx.x * blockDim.x + threadIdx.x;
    if (i >= N_EDGES) return;
    int s = ei[i];
    int d = ei[N_EDGES + i];
    atomicAdd(&cnt_td[d], 1);
    atomicAdd(&cnt_bu[s], 1);
}

// ---------------------------------------------------------------------------
// Exclusive scan of counts -> row offsets; also dinv = rsqrt(cnt+1).
__global__ void scan_dinv_kernel(const int* __restrict__ cnt0, const int* __restrict__ cnt1,
                                 int* off0, int* off1, float* dinv0, float* dinv1, int n) {
    const int* cnt = blockIdx.x ? cnt1 : cnt0;
    int* off       = blockIdx.x ? off1 : off0;
    float* dinv    = blockIdx.x ? dinv1 : dinv0;
    __shared__ int s[1024];
    int tid = threadIdx.x;
    int carry = 0;
    for (int base = 0; base < n; base += 1024) {
        int i = base + tid;
        int v = (i < n) ? cnt[i] : 0;
        if (i < n) dinv[i] = rsqrtf((float)v + 1.0f);
        s[tid] = v;
        __syncthreads();
        for (int o = 1; o < 1024; o <<= 1) {
            int t = (tid >= o) ? s[tid - o] : 0;
            __syncthreads();
            s[tid] += t;
            __syncthreads();
        }
        if (i < n) off[i] = carry + s[tid] - v;
        carry += s[1023];
        __syncthreads();
    }
}

// ---------------------------------------------------------------------------
__global__ void fill_kernel(const int* __restrict__ ei,
                            const int* __restrict__ off_td, int* cur_td, int* csr_td,
                            const int* __restrict__ off_bu, int* cur_bu, int* csr_bu) {
    int i = blockIdx.x * blockDim.x + threadIdx.x;
    if (i >= N_EDGES) return;
    int s = ei[i];
    int d = ei[N_EDGES + i];
    int p = atomicAdd(&cur_td[d], 1);
    csr_td[off_td[d] + p] = s;
    int q = atomicAdd(&cur_bu[s], 1);
    csr_bu[off_bu[s] + q] = d;
}

// ---------------------------------------------------------------------------
// Convert x f32 -> bf16 (packed), 4 elems/thread
__global__ void cvt_x_kernel(const float* __restrict__ x, ushort* __restrict__ xb) {
    int i = blockIdx.x * blockDim.x + threadIdx.x;  // one float4
    if ((size_t)i * 4 >= (size_t)N_NODES * F_IN) return;
    float4 f = ((const float4*)x)[i];
    ushort4 u;
    u.x = f2bf(f.x); u.y = f2bf(f.y); u.z = f2bf(f.z); u.w = f2bf(f.w);
    ((ushort4*)xb)[i] = u;
}

// ---------------------------------------------------------------------------
// Pre-transpose weights to Bt[n][k] bf16.
// Bt1: [256n][256k], n<128 -> td_W1[k][n], else bu_W1[k][n-128]
// Bt2: block-diagonal of td_W2 / bu_W2 (zeros off-block)
__global__ void prep_w_kernel(const float* __restrict__ td_W1, const float* __restrict__ bu_W1,
                              const float* __restrict__ td_W2, const float* __restrict__ bu_W2,
                              ushort* __restrict__ Bt1, ushort* __restrict__ Bt2) {
    int n = blockIdx.x;   // 0..255 output col
    int k = threadIdx.x;  // 0..255 reduction idx
    float w1 = (n < F_H) ? td_W1[(size_t)k * F_H + n] : bu_W1[(size_t)k * F_H + (n - F_H)];
    Bt1[(size_t)n * 256 + k] = f2bf(w1);
    float w2;
    if (n < F_H) w2 = (k < F_H) ? td_W2[(size_t)k * F_H + n] : 0.0f;
    else         w2 = (k >= F_H) ? bu_W2[(size_t)(k - F_H) * F_H + (n - F_H)] : 0.0f;
    Bt2[(size_t)n * 256 + k] = f2bf(w2);
}

// ---------------------------------------------------------------------------
// MFMA GEMM: C[M,256] = A[M,256] @ Bt^T, epilogue scales row by dinv of the
// block's branch and stores bf16. 128x128 tile, BK=32, 256 thr (4 waves),
// each wave: 32 rows x 128 cols via 2x8 of 16x16x32 MFMA.
#define LDSS 40  // ushort stride: 80 B = 5*16 B, keeps b128 alignment, 2-way banks (free)
__global__ __launch_bounds__(256) void gemm_mfma(
        const ushort* __restrict__ A, const ushort* __restrict__ Bt,
        ushort* __restrict__ C,
        const float* __restrict__ dinv_td, const float* __restrict__ dinv_bu, int M) {
    __shared__ ushort As[128 * LDSS];
    __shared__ ushort Bs[128 * LDSS];
    int tid = threadIdx.x;
    int bm = blockIdx.x * 128;
    int bn = blockIdx.y * 128;
    const float* dsel = blockIdx.y ? dinv_bu : dinv_td;
    int wave = tid >> 6, lane = tid & 63;
    int quad = lane >> 4, l16 = lane & 15;

    f32x4 acc[2][8];
    const f32x4 z4 = {0.f, 0.f, 0.f, 0.f};
#pragma unroll
    for (int i = 0; i < 2; i++)
#pragma unroll
        for (int j = 0; j < 8; j++) acc[i][j] = z4;

    // staging: 512 chunks of 16B per tile, 2 per thread
    int r0 = tid >> 2,        s0 = (tid & 3) * 8;
    int r1 = (tid + 256) >> 2, s1 = ((tid + 256) & 3) * 8;

    for (int kb = 0; kb < 8; kb++) {
        int k0 = kb * 32;
        short8 va0 = 0, va1 = 0;
        if (bm + r0 < M) va0 = *(const short8*)(A + (size_t)(bm + r0) * 256 + k0 + s0);
        if (bm + r1 < M) va1 = *(const short8*)(A + (size_t)(bm + r1) * 256 + k0 + s1);
        short8 vb0 = *(const short8*)(Bt + (size_t)(bn + r0) * 256 + k0 + s0);
        short8 vb1 = *(const short8*)(Bt + (size_t)(bn + r1) * 256 + k0 + s1);
        __syncthreads();  // protect previous iter's fragment reads
        *(short8*)(As + r0 * LDSS + s0) = va0;
        *(short8*)(As + r1 * LDSS + s1) = va1;
        *(short8*)(Bs + r0 * LDSS + s0) = vb0;
        *(short8*)(Bs + r1 * LDSS + s1) = vb1;
        __syncthreads();
        short8 af0 = *(const short8*)(As + (wave * 32 + l16) * LDSS + quad * 8);
        short8 af1 = *(const short8*)(As + (wave * 32 + 16 + l16) * LDSS + quad * 8);
#pragma unroll
        for (int ct = 0; ct < 8; ct++) {
            short8 bfr = *(const short8*)(Bs + (ct * 16 + l16) * LDSS + quad * 8);
            acc[0][ct] = __builtin_amdgcn_mfma_f32_16x16x32_bf16(af0, bfr, acc[0][ct], 0, 0, 0);
            acc[1][ct] = __builtin_amdgcn_mfma_f32_16x16x32_bf16(af1, bfr, acc[1][ct], 0, 0, 0);
        }
    }
    // epilogue: C/D layout col=lane&15, row=quad*4+reg
#pragma unroll
    for (int rt = 0; rt < 2; rt++) {
#pragma unroll
        for (int r = 0; r < 4; r++) {
            int row = bm + wave * 32 + rt * 16 + quad * 4 + r;
            if (row < M) {
                float dv = dsel[row];
#pragma unroll
                for (int ct = 0; ct < 8; ct++) {
                    int col = bn + ct * 16 + l16;
                    C[(size_t)row * 256 + col] = f2bf(acc[rt][ct][r] * dv);
                }
            }
        }
    }
}

// ---------------------------------------------------------------------------
// Pull aggregation on dinv-pre-scaled bf16 features.
// out[n,c] = dn*(linS[n,c] + sum_{src} linS[src,c]) + bias[c]
// block = 128 thr: wave0 = td (cols 0..127), wave1 = bu (cols 128..255);
// each lane covers 2 cols (one packed uint load per row).
template <int RELU, int OUT_BF16>
__global__ __launch_bounds__(128) void agg_kernel(
        const ushort* __restrict__ linS, void* __restrict__ outp,
        const int* __restrict__ csr_td, const int* __restrict__ off_td,
        const int* __restrict__ cnt_td, const float* __restrict__ dinv_td,
        const int* __restrict__ csr_bu, const int* __restrict__ off_bu,
        const int* __restrict__ cnt_bu, const float* __restrict__ dinv_bu,
        const float* __restrict__ b_td, const float* __restrict__ b_bu) {
    int n = blockIdx.x;
    int br = threadIdx.x >> 6;
    int lane = threadIdx.x & 63;
    const int* csr    = br ? csr_bu : csr_td;
    const int* off    = br ? off_bu : off_td;
    const int* cnt    = br ? cnt_bu : cnt_td;
    const float* dinv = br ? dinv_bu : dinv_td;
    const float* bias = br ? b_bu : b_td;
    size_t cbase = (size_t)br * F_H + lane * 2;

    uint v = *(const uint*)(linS + (size_t)n * F_CAT + cbase);  // self
    float a0 = bflo(v), a1 = bfhi(v);
    int s = off[n], e = s + cnt[n];
    int k = s;
    for (; k + 2 <= e; k += 2) {
        int i0 = csr[k], i1 = csr[k + 1];
        uint v0 = *(const uint*)(linS + (size_t)i0 * F_CAT + cbase);
        uint v1 = *(const uint*)(linS + (size_t)i1 * F_CAT + cbase);
        a0 += bflo(v0); a1 += bfhi(v0);
        a0 += bflo(v1); a1 += bfhi(v1);
    }
    if (k < e) {
        int i0 = csr[k];
        uint v0 = *(const uint*)(linS + (size_t)i0 * F_CAT + cbase);
        a0 += bflo(v0); a1 += bfhi(v0);
    }
    float dn = dinv[n];
    float o0 = a0 * dn + bias[lane * 2];
    float o1 = a1 * dn + bias[lane * 2 + 1];
    if (RELU) { o0 = fmaxf(o0, 0.f); o1 = fmaxf(o1, 0.f); }
    if (OUT_BF16) {
        uint p = (uint)f2bf(o0) | ((uint)f2bf(o1) << 16);
        *(uint*)((ushort*)outp + (size_t)n * F_CAT + cbase) = p;
    } else {
        float2 p = make_float2(o0, o1);
        *(float2*)((float*)outp + (size_t)n * F_CAT + cbase) = p;
    }
}

// ---------------------------------------------------------------------------
// Global add pool via sorted batch (binary search). Writes concat([bu, td]).
__global__ __launch_bounds__(256) void pool_kernel(const float* __restrict__ h2,
                                                   const int* __restrict__ batch,
                                                   float* __restrict__ pooled) {
    int g = blockIdx.x;
    int c = threadIdx.x;
    int lo = 0, hi = N_NODES;
    while (lo < hi) { int mid = (lo + hi) >> 1; if (batch[mid] < g) lo = mid + 1; else hi = mid; }
    int start = lo;
    lo = start; hi = N_NODES;
    while (lo < hi) { int mid = (lo + hi) >> 1; if (batch[mid] < g + 1) lo = mid + 1; else hi = mid; }
    int end = lo;
    int srcCol = (c < F_H) ? (F_H + c) : (c - F_H);
    float acc = 0.f;
    for (int n = start; n < end; n++) acc += h2[(size_t)n * F_CAT + srcCol];
    pooled[(size_t)g * F_CAT + c] = acc;
}

// ---------------------------------------------------------------------------
__global__ __launch_bounds__(256) void mlp_kernel(const float* __restrict__ pooled,
                                                  const float* __restrict__ pw1,
                                                  const float* __restrict__ pb1,
                                                  const float* __restrict__ pw2,
                                                  const float* __restrict__ pb2,
                                                  float* __restrict__ out) {
    int g = blockIdx.x;
    int tid = threadIdx.x;
    __shared__ float row[256];
    __shared__ float hid[256];
    row[tid] = pooled[(size_t)g * 256 + tid];
    __syncthreads();
    float acc = pb1[tid];
    for (int k = 0; k < 256; k++) acc += row[k] * pw1[(size_t)k * 256 + tid];
    hid[tid] = fmaxf(acc, 0.f);
    __syncthreads();
    if (tid < 128) {
        float o = pb2[tid];
        for (int k = 0; k < 256; k++) o += hid[k] * pw2[(size_t)k * 128 + tid];
        out[(size_t)g * 128 + tid] = o;
    }
}

// ---------------------------------------------------------------------------
extern "C" void kernel_launch(void* const* d_in, const int* in_sizes, int n_in,
                              void* d_out, int out_size, void* d_ws, size_t ws_size,
                              hipStream_t stream) {
    const float* x     = (const float*)d_in[0];
    const int*   ei    = (const int*)d_in[1];
    const int*   batch = (const int*)d_in[2];
    const float* td_W1 = (const float*)d_in[4];
    const float* td_b1 = (const float*)d_in[5];
    const float* td_W2 = (const float*)d_in[6];
    const float* td_b2 = (const float*)d_in[7];
    const float* bu_W1 = (const float*)d_in[8];
    const float* bu_b1 = (const float*)d_in[9];
    const float* bu_W2 = (const float*)d_in[10];
    const float* bu_b2 = (const float*)d_in[11];
    const float* pw1   = (const float*)d_in[12];
    const float* pb1   = (const float*)d_in[13];
    const float* pw2   = (const float*)d_in[14];
    const float* pb2   = (const float*)d_in[15];
    float* out = (float*)d_out;

    // ---- workspace carve ----
    char* p = (char*)d_ws;
    auto alloc = [&](size_t bytes) { void* r = (void*)p; p += (bytes + 255) & ~(size_t)255; return r; };
    int* zero_region = (int*)alloc((size_t)4 * N_NODES * sizeof(int));
    int* cnt_td = zero_region;
    int* cnt_bu = zero_region + N_NODES;
    int* cur_td = zero_region + 2 * N_NODES;
    int* cur_bu = zero_region + 3 * N_NODES;
    int* off_td = (int*)alloc((size_t)N_NODES * sizeof(int));
    int* off_bu = (int*)alloc((size_t)N_NODES * sizeof(int));
    float* dinv_td = (float*)alloc((size_t)N_NODES * sizeof(float));
    float* dinv_bu = (float*)alloc((size_t)N_NODES * sizeof(float));
    int* csr_td = (int*)alloc((size_t)N_EDGES * sizeof(int));
    int* csr_bu = (int*)alloc((size_t)N_EDGES * sizeof(int));
    ushort* Bt1 = (ushort*)alloc((size_t)256 * 256 * sizeof(ushort));
    ushort* Bt2 = (ushort*)alloc((size_t)256 * 256 * sizeof(ushort));
    // R region: xb (bf16, first half) shares lifetime-disjoint space with h2f (f32)
    void* R = alloc((size_t)N_NODES * F_CAT * sizeof(float));  // 51.2 MB
    ushort* xb  = (ushort*)R;
    float*  h2f = (float*)R;
    ushort* linb = (ushort*)alloc((size_t)N_NODES * F_CAT * sizeof(ushort));  // GEMM out (scaled)
    ushort* h1b  = (ushort*)alloc((size_t)N_NODES * F_CAT * sizeof(ushort));  // agg1 out
    float* pooled = (float*)alloc((size_t)N_GRAPHS * F_CAT * sizeof(float));

    hipMemsetAsync(zero_region, 0, (size_t)4 * N_NODES * sizeof(int), stream);

    // ---- graph structure ----
    deg_kernel<<<(N_EDGES + 255) / 256, 256, 0, stream>>>(ei, cnt_td, cnt_bu);
    scan_dinv_kernel<<<2, 1024, 0, stream>>>(cnt_td, cnt_bu, off_td, off_bu,
                                             dinv_td, dinv_bu, N_NODES);
    fill_kernel<<<(N_EDGES + 255) / 256, 256, 0, stream>>>(ei, off_td, cur_td, csr_td,
                                                           off_bu, cur_bu, csr_bu);

    // ---- bf16 conversions ----
    cvt_x_kernel<<<(N_NODES * F_IN / 4 + 255) / 256, 256, 0, stream>>>(x, xb);
    prep_w_kernel<<<256, 256, 0, stream>>>(td_W1, bu_W1, td_W2, bu_W2, Bt1, Bt2);

    dim3 gg((N_NODES + 127) / 128, 2);

    // ---- layer 1 ----
    gemm_mfma<<<gg, 256, 0, stream>>>(xb, Bt1, linb, dinv_td, dinv_bu, N_NODES);
    agg_kernel<1, 1><<<N_NODES, 128, 0, stream>>>(linb, h1b,
        csr_td, off_td, cnt_td, dinv_td, csr_bu, off_bu, cnt_bu, dinv_bu, td_b1, bu_b1);

    // ---- layer 2 (block-diagonal weights) ----
    gemm_mfma<<<gg, 256, 0, stream>>>(h1b, Bt2, linb, dinv_td, dinv_bu, N_NODES);
    agg_kernel<0, 0><<<N_NODES, 128, 0, stream>>>(linb, h2f,
        csr_td, off_td, cnt_td, dinv_td, csr_bu, off_bu, cnt_bu, dinv_bu, td_b2, bu_b2);

    // ---- pool + head ----
    pool_kernel<<<N_GRAPHS, 256, 0, stream>>>(h2f, batch, pooled);
    mlp_kernel<<<N_GRAPHS, 256, 0, stream>>>(pooled, pw1, pb1, pw2, pb2, out);
}

// Round 3
// 481.591 us; speedup vs baseline: 1.9368x; 1.3941x over previous
//
#include <hip/hip_runtime.h>

#define N_NODES 50000
#define N_PAD   50048   // 391*128, lets GEMM drop all row guards
#define N_EDGES 800000
#define N_GRAPHS 512
#define F_IN 256
#define F_H 128
#define F_CAT 256
#define NCH 49          // ceil(50000/1024) scan chunks

typedef __attribute__((ext_vector_type(8))) short short8;
typedef __attribute__((ext_vector_type(4))) float f32x4;
typedef unsigned int uint;
typedef unsigned short ushort;

static __device__ __forceinline__ ushort f2bf(float f) {
    uint u = __float_as_uint(f);
    u += 0x7FFF + ((u >> 16) & 1);  // RNE
    return (ushort)(u >> 16);
}
static __device__ __forceinline__ float bflo(uint v) { return __uint_as_float(v << 16); }
static __device__ __forceinline__ float bfhi(uint v) { return __uint_as_float(v & 0xFFFF0000u); }

// async global->LDS, 16B per lane; lds base must be wave-uniform
#define GLL(g, l) __builtin_amdgcn_global_load_lds( \
    (const __attribute__((address_space(1))) unsigned int*)(g), \
    (__attribute__((address_space(3))) unsigned int*)(l), 16, 0, 0)

// ---------------------------------------------------------------------------
__global__ void deg_kernel(const int* __restrict__ ei, int* cnt_td, int* cnt_bu) {
    int i = blockIdx.x * blockDim.x + threadIdx.x;
    if (i >= N_EDGES) return;
    int s = ei[i];
    int d = ei[N_EDGES + i];
    atomicAdd(&cnt_td[d], 1);
    atomicAdd(&cnt_bu[s], 1);
}

// ---------------------------------------------------------------------------
// Scan stage 1: per-chunk (1024 elems) sums. grid (NCH, 2), 256 thr.
__global__ __launch_bounds__(256) void hist_part_kernel(const int* __restrict__ cnt_td,
                                                        const int* __restrict__ cnt_bu,
                                                        int* __restrict__ chunk_sum) {
    int arr = blockIdx.y;
    const int* cnt = arr ? cnt_bu : cnt_td;
    int tid = threadIdx.x;
    int base = blockIdx.x * 1024 + tid * 4;
    int s = 0;
#pragma unroll
    for (int j = 0; j < 4; j++) {
        int idx = base + j;
        if (idx < N_NODES) s += cnt[idx];
    }
    __shared__ int sm[256];
    sm[tid] = s;
    __syncthreads();
    for (int o = 128; o > 0; o >>= 1) {
        if (tid < o) sm[tid] += sm[tid + o];
        __syncthreads();
    }
    if (tid == 0) chunk_sum[arr * 64 + blockIdx.x] = sm[0];
}

// Scan stage 2: exclusive scan of chunk sums (both arrays). 1 block, 128 thr.
__global__ __launch_bounds__(128) void scan_chunks_kernel(const int* __restrict__ chunk_sum,
                                                          int* __restrict__ chunk_off,
                                                          int* off_td, int* off_bu) {
    int lane = threadIdx.x & 63;
    int arr = threadIdx.x >> 6;
    int self = (lane < NCH) ? chunk_sum[arr * 64 + lane] : 0;
    int v = self;
    for (int o = 1; o < 64; o <<= 1) {
        int u = __shfl_up(v, o);
        if (lane >= o) v += u;
    }
    if (lane < NCH) chunk_off[arr * 64 + lane] = v - self;  // exclusive
    if (lane == 0) (arr ? off_bu : off_td)[N_NODES] = N_EDGES;
}

// Scan stage 3: final per-element exclusive offsets + dinv. grid (NCH, 2), 256 thr.
__global__ __launch_bounds__(256) void scan_final_kernel(const int* __restrict__ cnt_td,
                                                         const int* __restrict__ cnt_bu,
                                                         const int* __restrict__ chunk_off,
                                                         int* off_td, int* off_bu,
                                                         float* dinv_td, float* dinv_bu) {
    int arr = blockIdx.y;
    const int* cnt = arr ? cnt_bu : cnt_td;
    int* off       = arr ? off_bu : off_td;
    float* dinv    = arr ? dinv_bu : dinv_td;
    int tid = threadIdx.x;
    int base = blockIdx.x * 1024 + tid * 4;
    int v[4];
    int s = 0;
#pragma unroll
    for (int j = 0; j < 4; j++) {
        int idx = base + j;
        v[j] = (idx < N_NODES) ? cnt[idx] : 0;
        s += v[j];
    }
    __shared__ int sm[256];
    sm[tid] = s;
    __syncthreads();
    for (int o = 1; o < 256; o <<= 1) {
        int t = (tid >= o) ? sm[tid - o] : 0;
        __syncthreads();
        sm[tid] += t;
        __syncthreads();
    }
    int run = chunk_off[arr * 64 + blockIdx.x] + sm[tid] - s;  // exclusive prefix
#pragma unroll
    for (int j = 0; j < 4; j++) {
        int idx = base + j;
        if (idx < N_NODES) {
            off[idx] = run;
            dinv[idx] = rsqrtf((float)v[j] + 1.0f);
            run += v[j];
        }
    }
}

// ---------------------------------------------------------------------------
// CSR fill: consumes cnt via atomic decrement (slot = off + old - 1).
__global__ void fill_kernel(const int* __restrict__ ei,
                            const int* __restrict__ off_td, int* cnt_td, int* csr_td,
                            const int* __restrict__ off_bu, int* cnt_bu, int* csr_bu) {
    int i = blockIdx.x * blockDim.x + threadIdx.x;
    if (i >= N_EDGES) return;
    int s = ei[i];
    int d = ei[N_EDGES + i];
    int p = atomicAdd(&cnt_td[d], -1);
    csr_td[off_td[d] + p - 1] = s;
    int q = atomicAdd(&cnt_bu[s], -1);
    csr_bu[off_bu[s] + q - 1] = d;
}

// ---------------------------------------------------------------------------
// x f32 -> bf16, zero-fill pad rows [50000,50048)
__global__ void cvt_x_kernel(const float* __restrict__ x, ushort* __restrict__ xb) {
    size_t i = (size_t)blockIdx.x * blockDim.x + threadIdx.x;  // float4 index
    ushort4 u = {0, 0, 0, 0};
    if (i < (size_t)N_NODES * (F_IN / 4)) {
        float4 f = ((const float4*)x)[i];
        u.x = f2bf(f.x); u.y = f2bf(f.y); u.z = f2bf(f.z); u.w = f2bf(f.w);
    }
    ((ushort4*)xb)[i] = u;  // grid covers exactly N_PAD*F_IN/4
}

// ---------------------------------------------------------------------------
__global__ void prep_w_kernel(const float* __restrict__ td_W1, const float* __restrict__ bu_W1,
                              const float* __restrict__ td_W2, const float* __restrict__ bu_W2,
                              ushort* __restrict__ Bt1, ushort* __restrict__ Bt2) {
    int n = blockIdx.x;
    int k = threadIdx.x;
    float w1 = (n < F_H) ? td_W1[(size_t)k * F_H + n] : bu_W1[(size_t)k * F_H + (n - F_H)];
    Bt1[(size_t)n * 256 + k] = f2bf(w1);
    float w2;
    if (n < F_H) w2 = (k < F_H) ? td_W2[(size_t)k * F_H + n] : 0.0f;
    else         w2 = (k >= F_H) ? bu_W2[(size_t)(k - F_H) * F_H + (n - F_H)] : 0.0f;
    Bt2[(size_t)n * 256 + k] = f2bf(w2);
}

// ---------------------------------------------------------------------------
// MFMA GEMM with global_load_lds staging. M = N_PAD (no guards), N=256 via
// grid.y=2, K=256. 128x128 tile, BK=32, 256 thr / 4 waves.
// LDS rows are 32 ushort (64 B): frag-read bank clusters uniform, no padding.
__global__ __launch_bounds__(256) void gemm_mfma(
        const ushort* __restrict__ A, const ushort* __restrict__ Bt,
        ushort* __restrict__ C,
        const float* __restrict__ dinv_td, const float* __restrict__ dinv_bu) {
    __shared__ __align__(16) ushort As[128 * 32];
    __shared__ __align__(16) ushort Bs[128 * 32];
    int tid = threadIdx.x;
    int wave = tid >> 6, lane = tid & 63, quad = lane >> 4, l16 = lane & 15;
    size_t bm = (size_t)blockIdx.x * 128;
    size_t bn = (size_t)blockIdx.y * 128;
    const float* dsel = blockIdx.y ? dinv_bu : dinv_td;

    f32x4 acc[2][8];
    const f32x4 z4 = {0.f, 0.f, 0.f, 0.f};
#pragma unroll
    for (int i = 0; i < 2; i++)
#pragma unroll
        for (int j = 0; j < 8; j++) acc[i][j] = z4;

    // staging chunk for this lane: c = cb + lane; chunk c covers row c>>2, kseg c&3
    int cb0 = wave * 64;
    int cb1 = 256 + wave * 64;
    int c0 = cb0 + lane, c1 = cb1 + lane;
    int r0 = c0 >> 2, s0 = (c0 & 3) * 8;
    int r1 = c1 >> 2, s1 = (c1 & 3) * 8;
    const ushort* a0p = A + (bm + r0) * 256 + s0;
    const ushort* a1p = A + (bm + r1) * 256 + s1;
    const ushort* b0p = Bt + (bn + r0) * 256 + s0;
    const ushort* b1p = Bt + (bn + r1) * 256 + s1;
    ushort* lA0 = As + cb0 * 8;  // wave-uniform bases
    ushort* lA1 = As + cb1 * 8;
    ushort* lB0 = Bs + cb0 * 8;
    ushort* lB1 = Bs + cb1 * 8;

    for (int kb = 0; kb < 8; kb++) {
        int k0 = kb * 32;
        __syncthreads();  // previous iter's frag reads done
        GLL(a0p + k0, lA0);
        GLL(a1p + k0, lA1);
        GLL(b0p + k0, lB0);
        GLL(b1p + k0, lB1);
        __syncthreads();  // drains vmcnt, data in LDS
        short8 af0 = *(const short8*)(As + (wave * 32 + l16) * 32 + quad * 8);
        short8 af1 = *(const short8*)(As + (wave * 32 + 16 + l16) * 32 + quad * 8);
#pragma unroll
        for (int ct = 0; ct < 8; ct++) {
            short8 bfr = *(const short8*)(Bs + (ct * 16 + l16) * 32 + quad * 8);
            acc[0][ct] = __builtin_amdgcn_mfma_f32_16x16x32_bf16(af0, bfr, acc[0][ct], 0, 0, 0);
            acc[1][ct] = __builtin_amdgcn_mfma_f32_16x16x32_bf16(af1, bfr, acc[1][ct], 0, 0, 0);
        }
    }
#pragma unroll
    for (int rt = 0; rt < 2; rt++) {
#pragma unroll
        for (int r = 0; r < 4; r++) {
            size_t row = bm + wave * 32 + rt * 16 + quad * 4 + r;
            float dv = dsel[row];
#pragma unroll
            for (int ct = 0; ct < 8; ct++) {
                C[row * 256 + bn + ct * 16 + l16] = f2bf(acc[rt][ct][r] * dv);
            }
        }
    }
}

// ---------------------------------------------------------------------------
// unrolled gather of one node's neighbor sum over 2 packed bf16 cols
static __device__ __forceinline__ void gather_row(const ushort* __restrict__ base,
                                                  const int* __restrict__ csr,
                                                  int s, int e, float& a0, float& a1) {
    float p0 = 0, p1 = 0, q0 = 0, q1 = 0, r0 = 0, r1 = 0;
    int k = s;
    for (; k + 4 <= e; k += 4) {
        int i0 = csr[k], i1 = csr[k + 1], i2 = csr[k + 2], i3 = csr[k + 3];
        uint v0 = *(const uint*)(base + (size_t)i0 * F_CAT);
        uint v1 = *(const uint*)(base + (size_t)i1 * F_CAT);
        uint v2 = *(const uint*)(base + (size_t)i2 * F_CAT);
        uint v3 = *(const uint*)(base + (size_t)i3 * F_CAT);
        a0 += bflo(v0); a1 += bfhi(v0);
        p0 += bflo(v1); p1 += bfhi(v1);
        q0 += bflo(v2); q1 += bfhi(v2);
        r0 += bflo(v3); r1 += bfhi(v3);
    }
    for (; k < e; k++) {
        int i0 = csr[k];
        uint v0 = *(const uint*)(base + (size_t)i0 * F_CAT);
        a0 += bflo(v0); a1 += bfhi(v0);
    }
    a0 += (p0 + q0) + r0;
    a1 += (p1 + q1) + r1;
}

// ---------------------------------------------------------------------------
// Layer-1 aggregation: relu(dn*(self+neigh)+b) -> bf16 h1. 1 node/block.
__global__ __launch_bounds__(128) void agg1_kernel(
        const ushort* __restrict__ linS, ushort* __restrict__ h1b,
        const int* __restrict__ csr_td, const int* __restrict__ off_td,
        const float* __restrict__ dinv_td,
        const int* __restrict__ csr_bu, const int* __restrict__ off_bu,
        const float* __restrict__ dinv_bu,
        const float* __restrict__ b_td, const float* __restrict__ b_bu) {
    int n = blockIdx.x;
    int br = threadIdx.x >> 6, lane = threadIdx.x & 63;
    const int* csr    = br ? csr_bu : csr_td;
    const int* off    = br ? off_bu : off_td;
    const float* dinv = br ? dinv_bu : dinv_td;
    const float* bias = br ? b_bu : b_td;
    size_t cbase = (size_t)br * F_H + lane * 2;
    const ushort* base = linS + cbase;

    uint v = *(const uint*)(base + (size_t)n * F_CAT);
    float a0 = bflo(v), a1 = bfhi(v);
    gather_row(base, csr, off[n], off[n + 1], a0, a1);
    float dn = dinv[n];
    float o0 = fmaxf(a0 * dn + bias[lane * 2], 0.f);
    float o1 = fmaxf(a1 * dn + bias[lane * 2 + 1], 0.f);
    uint pk = (uint)f2bf(o0) | ((uint)f2bf(o1) << 16);
    *(uint*)(h1b + (size_t)n * F_CAT + cbase) = pk;
}

// ---------------------------------------------------------------------------
// Layer-2 aggregation fused with global_add_pool. 8 nodes/block; batch is
// sorted, so we accumulate per-graph segments and flush with one atomic pair.
// pooled layout: concat([bu, td]) -> td cols go to 128.., bu cols to 0..
__global__ __launch_bounds__(128) void agg2_pool_kernel(
        const ushort* __restrict__ linS, float* __restrict__ pooled,
        const int* __restrict__ batch,
        const int* __restrict__ csr_td, const int* __restrict__ off_td,
        const float* __restrict__ dinv_td,
        const int* __restrict__ csr_bu, const int* __restrict__ off_bu,
        const float* __restrict__ dinv_bu,
        const float* __restrict__ b_td, const float* __restrict__ b_bu) {
    int n0 = blockIdx.x * 8;
    int br = threadIdx.x >> 6, lane = threadIdx.x & 63;
    const int* csr    = br ? csr_bu : csr_td;
    const int* off    = br ? off_bu : off_td;
    const float* dinv = br ? dinv_bu : dinv_td;
    const float* bias = br ? b_bu : b_td;
    size_t cbase = (size_t)br * F_H + lane * 2;
    const ushort* base = linS + cbase;
    int pcol = (br ? 0 : F_H) + lane * 2;
    float bs0 = bias[lane * 2], bs1 = bias[lane * 2 + 1];

    float acc0 = 0.f, acc1 = 0.f;
    int gcur = batch[n0];
#pragma unroll
    for (int j = 0; j < 8; j++) {
        int n = n0 + j;
        int g = batch[n];
        if (g != gcur) {  // wave-uniform branch
            unsafeAtomicAdd(&pooled[(size_t)gcur * F_CAT + pcol], acc0);
            unsafeAtomicAdd(&pooled[(size_t)gcur * F_CAT + pcol + 1], acc1);
            acc0 = acc1 = 0.f;
            gcur = g;
        }
        uint v = *(const uint*)(base + (size_t)n * F_CAT);
        float a0 = bflo(v), a1 = bfhi(v);
        gather_row(base, csr, off[n], off[n + 1], a0, a1);
        float dn = dinv[n];
        acc0 += a0 * dn + bs0;
        acc1 += a1 * dn + bs1;
    }
    unsafeAtomicAdd(&pooled[(size_t)gcur * F_CAT + pcol], acc0);
    unsafeAtomicAdd(&pooled[(size_t)gcur * F_CAT + pcol + 1], acc1);
}

// ---------------------------------------------------------------------------
__global__ __launch_bounds__(256) void mlp_kernel(const float* __restrict__ pooled,
                                                  const float* __restrict__ pw1,
                                                  const float* __restrict__ pb1,
                                                  const float* __restrict__ pw2,
                                                  const float* __restrict__ pb2,
                                                  float* __restrict__ out) {
    int g = blockIdx.x;
    int tid = threadIdx.x;
    __shared__ float row[256];
    __shared__ float hid[256];
    row[tid] = pooled[(size_t)g * 256 + tid];
    __syncthreads();
    float acc = pb1[tid];
    for (int k = 0; k < 256; k++) acc += row[k] * pw1[(size_t)k * 256 + tid];
    hid[tid] = fmaxf(acc, 0.f);
    __syncthreads();
    if (tid < 128) {
        float o = pb2[tid];
        for (int k = 0; k < 256; k++) o += hid[k] * pw2[(size_t)k * 128 + tid];
        out[(size_t)g * 128 + tid] = o;
    }
}

// ---------------------------------------------------------------------------
extern "C" void kernel_launch(void* const* d_in, const int* in_sizes, int n_in,
                              void* d_out, int out_size, void* d_ws, size_t ws_size,
                              hipStream_t stream) {
    const float* x     = (const float*)d_in[0];
    const int*   ei    = (const int*)d_in[1];
    const int*   batch = (const int*)d_in[2];
    const float* td_W1 = (const float*)d_in[4];
    const float* td_b1 = (const float*)d_in[5];
    const float* td_W2 = (const float*)d_in[6];
    const float* td_b2 = (const float*)d_in[7];
    const float* bu_W1 = (const float*)d_in[8];
    const float* bu_b1 = (const float*)d_in[9];
    const float* bu_W2 = (const float*)d_in[10];
    const float* bu_b2 = (const float*)d_in[11];
    const float* pw1   = (const float*)d_in[12];
    const float* pb1   = (const float*)d_in[13];
    const float* pw2   = (const float*)d_in[14];
    const float* pb2   = (const float*)d_in[15];
    float* out = (float*)d_out;

    // ---- workspace carve ----
    char* p = (char*)d_ws;
    auto alloc = [&](size_t bytes) { void* r = (void*)p; p += (bytes + 255) & ~(size_t)255; return r; };
    int* cnt_td = (int*)alloc((size_t)2 * N_NODES * sizeof(int));  // memset region
    int* cnt_bu = cnt_td + N_NODES;
    int* off_td = (int*)alloc((size_t)(N_NODES + 1) * sizeof(int));
    int* off_bu = (int*)alloc((size_t)(N_NODES + 1) * sizeof(int));
    float* dinv_td = (float*)alloc((size_t)N_PAD * sizeof(float));
    float* dinv_bu = (float*)alloc((size_t)N_PAD * sizeof(float));
    int* chunk_sum = (int*)alloc(128 * sizeof(int));
    int* chunk_off = (int*)alloc(128 * sizeof(int));
    int* csr_td = (int*)alloc((size_t)N_EDGES * sizeof(int));
    int* csr_bu = (int*)alloc((size_t)N_EDGES * sizeof(int));
    ushort* Bt1 = (ushort*)alloc((size_t)256 * 256 * sizeof(ushort));
    ushort* Bt2 = (ushort*)alloc((size_t)256 * 256 * sizeof(ushort));
    ushort* xb   = (ushort*)alloc((size_t)N_PAD * F_CAT * sizeof(ushort));
    ushort* linb = (ushort*)alloc((size_t)N_PAD * F_CAT * sizeof(ushort));
    ushort* h1b  = (ushort*)alloc((size_t)N_PAD * F_CAT * sizeof(ushort));
    float* pooled = (float*)alloc((size_t)N_GRAPHS * F_CAT * sizeof(float));  // memset

    hipMemsetAsync(cnt_td, 0, (size_t)2 * N_NODES * sizeof(int), stream);
    hipMemsetAsync(pooled, 0, (size_t)N_GRAPHS * F_CAT * sizeof(float), stream);

    // ---- graph structure ----
    deg_kernel<<<(N_EDGES + 255) / 256, 256, 0, stream>>>(ei, cnt_td, cnt_bu);
    hist_part_kernel<<<dim3(NCH, 2), 256, 0, stream>>>(cnt_td, cnt_bu, chunk_sum);
    scan_chunks_kernel<<<1, 128, 0, stream>>>(chunk_sum, chunk_off, off_td, off_bu);
    scan_final_kernel<<<dim3(NCH, 2), 256, 0, stream>>>(cnt_td, cnt_bu, chunk_off,
                                                        off_td, off_bu, dinv_td, dinv_bu);
    fill_kernel<<<(N_EDGES + 255) / 256, 256, 0, stream>>>(ei, off_td, cnt_td, csr_td,
                                                           off_bu, cnt_bu, csr_bu);

    // ---- bf16 conversions ----
    cvt_x_kernel<<<(N_PAD * F_IN / 4) / 256, 256, 0, stream>>>(x, xb);
    prep_w_kernel<<<256, 256, 0, stream>>>(td_W1, bu_W1, td_W2, bu_W2, Bt1, Bt2);

    dim3 gg(N_PAD / 128, 2);

    // ---- layer 1 ----
    gemm_mfma<<<gg, 256, 0, stream>>>(xb, Bt1, linb, dinv_td, dinv_bu);
    agg1_kernel<<<N_NODES, 128, 0, stream>>>(linb, h1b,
        csr_td, off_td, dinv_td, csr_bu, off_bu, dinv_bu, td_b1, bu_b1);

    // ---- layer 2 + pool ----
    gemm_mfma<<<gg, 256, 0, stream>>>(h1b, Bt2, linb, dinv_td, dinv_bu);
    agg2_pool_kernel<<<N_NODES / 8, 128, 0, stream>>>(linb, pooled, batch,
        csr_td, off_td, dinv_td, csr_bu, off_bu, dinv_bu, td_b2, bu_b2);

    // ---- projection head ----
    mlp_kernel<<<N_GRAPHS, 256, 0, stream>>>(pooled, pw1, pb1, pw2, pb2, out);
}

// Round 4
// 372.103 us; speedup vs baseline: 2.5067x; 1.2942x over previous
//
#include <hip/hip_runtime.h>

#define N_NODES 50000
#define N_PAD   50048   // 391*128, GEMM drops all row guards
#define N_EDGES 800000
#define N_GRAPHS 512
#define F_IN 256
#define F_H 128
#define F_CAT 256

// bucketed CSR build
#define BSHIFT 9
#define NB 98           // ceil(50000/512) buckets
#define CAP 10240       // edge capacity per bucket (mean 8163, 23 sigma slack)
#define EPB 3125        // edges per scatter block (256 blocks)

typedef __attribute__((ext_vector_type(8))) short short8;
typedef __attribute__((ext_vector_type(4))) float f32x4;
typedef unsigned int uint;
typedef unsigned short ushort;

static __device__ __forceinline__ ushort f2bf(float f) {
    uint u = __float_as_uint(f);
    u += 0x7FFF + ((u >> 16) & 1);  // RNE
    return (ushort)(u >> 16);
}
static __device__ __forceinline__ float bflo(uint v) { return __uint_as_float(v << 16); }
static __device__ __forceinline__ float bfhi(uint v) { return __uint_as_float(v & 0xFFFF0000u); }

// async global->LDS, 16B per lane; lds base must be wave-uniform
#define GLL(g, l) __builtin_amdgcn_global_load_lds( \
    (const __attribute__((address_space(1))) unsigned int*)(g), \
    (__attribute__((address_space(3))) unsigned int*)(l), 16, 0, 0)

// ---------------------------------------------------------------------------
// init per-bucket global cursors to bucket*CAP
__global__ void init_gcur_kernel(int* gcur) {
    int t = threadIdx.x;
    if (t < 2 * NB) gcur[t] = (t % NB) * CAP;
}

// ---------------------------------------------------------------------------
// S1: bucket-scatter edges. Each block: LDS histogram over (dir,bucket), one
// global atomicAdd per (block,bucket) to reserve a run, then scatter packed
// (endpoint | localNode<<16) into bucket-major ebuf.
__global__ __launch_bounds__(256) void csr_scatter_kernel(
        const int* __restrict__ ei, int* __restrict__ gcur,
        uint* __restrict__ ebuf_td, uint* __restrict__ ebuf_bu) {
    __shared__ int lcnt[256];   // [dir*128 + bucket]
    __shared__ int lbase[256];
    int tid = threadIdx.x;
    lcnt[tid] = 0;
    __syncthreads();
    int e0 = blockIdx.x * EPB;
    for (int k = tid; k < EPB; k += 256) {
        int i = e0 + k;
        int s = ei[i], d = ei[N_EDGES + i];
        atomicAdd(&lcnt[d >> BSHIFT], 1);
        atomicAdd(&lcnt[128 + (s >> BSHIFT)], 1);
    }
    __syncthreads();
    if (tid < 2 * NB) {
        int dir = tid / NB, b = tid % NB;
        int c = lcnt[dir * 128 + b];
        lbase[dir * 128 + b] = c ? atomicAdd(&gcur[dir * NB + b], c) : 0;
    }
    __syncthreads();
    lcnt[tid] = 0;
    __syncthreads();
    for (int k = tid; k < EPB; k += 256) {
        int i = e0 + k;
        int s = ei[i], d = ei[N_EDGES + i];
        int bd = d >> BSHIFT, bs = s >> BSHIFT;
        int p = atomicAdd(&lcnt[bd], 1) + lbase[bd];
        ebuf_td[p] = (uint)s | ((uint)(d & 511) << 16);
        int q = atomicAdd(&lcnt[128 + bs], 1) + lbase[128 + bs];
        ebuf_bu[q] = (uint)d | ((uint)(s & 511) << 16);
    }
}

// ---------------------------------------------------------------------------
// S2: per-(bucket,dir) CSR build. LDS node histogram -> scan -> off/deg/dinv,
// then bucket-local csr scatter (all writes within a ~33 KB window).
__global__ __launch_bounds__(256) void csr_build_kernel(
        const uint* __restrict__ ebuf_td, const uint* __restrict__ ebuf_bu,
        const int* __restrict__ gcur,
        int* off_td, int* off_bu, ushort* deg_td, ushort* deg_bu,
        float* dinv_td, float* dinv_bu, ushort* csr_td, ushort* csr_bu) {
    int b = blockIdx.x, dir = blockIdx.y;
    const uint* ebuf = dir ? ebuf_bu : ebuf_td;
    int* off     = dir ? off_bu : off_td;
    ushort* deg  = dir ? deg_bu : deg_td;
    float* dinv  = dir ? dinv_bu : dinv_td;
    ushort* csr  = dir ? csr_bu : csr_td;
    __shared__ int cntL[512], offL[512], sm[256];
    int tid = threadIdx.x;
    cntL[tid] = 0; cntL[tid + 256] = 0;
    __syncthreads();
    int rbeg = b * CAP;
    int rend = gcur[dir * NB + b];
    for (int k = rbeg + tid; k < rend; k += 256)
        atomicAdd(&cntL[ebuf[k] >> 16], 1);
    __syncthreads();
    int a0 = cntL[tid * 2], a1 = cntL[tid * 2 + 1];
    int ps = a0 + a1;
    sm[tid] = ps;
    __syncthreads();
    for (int o = 1; o < 256; o <<= 1) {
        int u = (tid >= o) ? sm[tid - o] : 0;
        __syncthreads();
        sm[tid] += u;
        __syncthreads();
    }
    int excl = sm[tid] - ps;
    offL[tid * 2] = excl;
    offL[tid * 2 + 1] = excl + a0;
    __syncthreads();
    int nbase = b << BSHIFT;
#pragma unroll
    for (int j = 0; j < 2; j++) {
        int nloc = tid + j * 256;
        int n = nbase + nloc;
        if (n < N_NODES) {
            off[n] = rbeg + offL[nloc];
            int c = cntL[nloc];
            deg[n] = (ushort)c;
            dinv[n] = rsqrtf((float)c + 1.0f);
        }
    }
    // cursors start at local exclusive offsets
    cntL[tid] = offL[tid];
    cntL[tid + 256] = offL[tid + 256];
    __syncthreads();
    for (int k = rbeg + tid; k < rend; k += 256) {
        uint e = ebuf[k];
        int slot = atomicAdd(&cntL[e >> 16], 1);
        csr[rbeg + slot] = (ushort)(e & 0xFFFF);
    }
}

// ---------------------------------------------------------------------------
// x f32 -> bf16, zero-fill pad rows
__global__ void cvt_x_kernel(const float* __restrict__ x, ushort* __restrict__ xb) {
    size_t i = (size_t)blockIdx.x * blockDim.x + threadIdx.x;  // float4 index
    ushort4 u = {0, 0, 0, 0};
    if (i < (size_t)N_NODES * (F_IN / 4)) {
        float4 f = ((const float4*)x)[i];
        u.x = f2bf(f.x); u.y = f2bf(f.y); u.z = f2bf(f.z); u.w = f2bf(f.w);
    }
    ((ushort4*)xb)[i] = u;
}

// ---------------------------------------------------------------------------
// Bt1: [256n][256k]; Bt2: [256n][128k] (block-diagonal collapsed to K=128)
__global__ void prep_w_kernel(const float* __restrict__ td_W1, const float* __restrict__ bu_W1,
                              const float* __restrict__ td_W2, const float* __restrict__ bu_W2,
                              ushort* __restrict__ Bt1, ushort* __restrict__ Bt2) {
    int n = blockIdx.x;
    int k = threadIdx.x;
    float w1 = (n < F_H) ? td_W1[(size_t)k * F_H + n] : bu_W1[(size_t)k * F_H + (n - F_H)];
    Bt1[(size_t)n * 256 + k] = f2bf(w1);
    if (k < 128) {
        float w2 = (n < F_H) ? td_W2[(size_t)k * F_H + n]
                             : bu_W2[(size_t)k * F_H + (n - F_H)];
        Bt2[(size_t)n * 128 + k] = f2bf(w2);
    }
}

// ---------------------------------------------------------------------------
// MFMA GEMM, global_load_lds staging. 128x128 tile, BK=32, 256 thr / 4 waves.
// kLen=256/128; aSplit=1 makes A read cols [bn, bn+kLen) (block-diag layer 2).
__global__ __launch_bounds__(256) void gemm_mfma(
        const ushort* __restrict__ A, const ushort* __restrict__ Bt,
        ushort* __restrict__ C,
        const float* __restrict__ dinv_td, const float* __restrict__ dinv_bu,
        int kLen, int ldb, int aSplit) {
    __shared__ __align__(16) ushort As[128 * 32];
    __shared__ __align__(16) ushort Bs[128 * 32];
    int tid = threadIdx.x;
    int wave = tid >> 6, lane = tid & 63, quad = lane >> 4, l16 = lane & 15;
    size_t bm = (size_t)blockIdx.x * 128;
    size_t bn = (size_t)blockIdx.y * 128;
    const float* dsel = blockIdx.y ? dinv_bu : dinv_td;
    int aOff = aSplit ? (int)bn : 0;

    f32x4 acc[2][8];
    const f32x4 z4 = {0.f, 0.f, 0.f, 0.f};
#pragma unroll
    for (int i = 0; i < 2; i++)
#pragma unroll
        for (int j = 0; j < 8; j++) acc[i][j] = z4;

    int cb0 = wave * 64;
    int cb1 = 256 + wave * 64;
    int c0 = cb0 + lane, c1 = cb1 + lane;
    int r0 = c0 >> 2, s0 = (c0 & 3) * 8;
    int r1 = c1 >> 2, s1 = (c1 & 3) * 8;
    const ushort* a0p = A + (bm + r0) * 256 + aOff + s0;
    const ushort* a1p = A + (bm + r1) * 256 + aOff + s1;
    const ushort* b0p = Bt + (bn + r0) * ldb + s0;
    const ushort* b1p = Bt + (bn + r1) * ldb + s1;
    ushort* lA0 = As + cb0 * 8;
    ushort* lA1 = As + cb1 * 8;
    ushort* lB0 = Bs + cb0 * 8;
    ushort* lB1 = Bs + cb1 * 8;

    int nkb = kLen >> 5;
    for (int kb = 0; kb < nkb; kb++) {
        int k0 = kb * 32;
        __syncthreads();
        GLL(a0p + k0, lA0);
        GLL(a1p + k0, lA1);
        GLL(b0p + k0, lB0);
        GLL(b1p + k0, lB1);
        __syncthreads();
        short8 af0 = *(const short8*)(As + (wave * 32 + l16) * 32 + quad * 8);
        short8 af1 = *(const short8*)(As + (wave * 32 + 16 + l16) * 32 + quad * 8);
#pragma unroll
        for (int ct = 0; ct < 8; ct++) {
            short8 bfr = *(const short8*)(Bs + (ct * 16 + l16) * 32 + quad * 8);
            acc[0][ct] = __builtin_amdgcn_mfma_f32_16x16x32_bf16(af0, bfr, acc[0][ct], 0, 0, 0);
            acc[1][ct] = __builtin_amdgcn_mfma_f32_16x16x32_bf16(af1, bfr, acc[1][ct], 0, 0, 0);
        }
    }
#pragma unroll
    for (int rt = 0; rt < 2; rt++) {
#pragma unroll
        for (int r = 0; r < 4; r++) {
            size_t row = bm + wave * 32 + rt * 16 + quad * 4 + r;
            float dv = dsel[row];
#pragma unroll
            for (int ct = 0; ct < 8; ct++) {
                C[row * 256 + bn + ct * 16 + l16] = f2bf(acc[rt][ct][r] * dv);
            }
        }
    }
}

// ---------------------------------------------------------------------------
// unrolled gather of one node's neighbor sum over 2 packed bf16 cols
static __device__ __forceinline__ void gather_row(const ushort* __restrict__ base,
                                                  const ushort* __restrict__ csr,
                                                  int s, int e, float& a0, float& a1) {
    float p0 = 0, p1 = 0, q0 = 0, q1 = 0, r0 = 0, r1 = 0;
    int k = s;
    for (; k + 4 <= e; k += 4) {
        int i0 = csr[k], i1 = csr[k + 1], i2 = csr[k + 2], i3 = csr[k + 3];
        uint v0 = *(const uint*)(base + (size_t)i0 * F_CAT);
        uint v1 = *(const uint*)(base + (size_t)i1 * F_CAT);
        uint v2 = *(const uint*)(base + (size_t)i2 * F_CAT);
        uint v3 = *(const uint*)(base + (size_t)i3 * F_CAT);
        a0 += bflo(v0); a1 += bfhi(v0);
        p0 += bflo(v1); p1 += bfhi(v1);
        q0 += bflo(v2); q1 += bfhi(v2);
        r0 += bflo(v3); r1 += bfhi(v3);
    }
    for (; k < e; k++) {
        int i0 = csr[k];
        uint v0 = *(const uint*)(base + (size_t)i0 * F_CAT);
        a0 += bflo(v0); a1 += bfhi(v0);
    }
    a0 += (p0 + q0) + r0;
    a1 += (p1 + q1) + r1;
}

// ---------------------------------------------------------------------------
// Layer-1 aggregation: relu(dn*(self+neigh)+b) -> bf16 h1. 1 node/block.
__global__ __launch_bounds__(128) void agg1_kernel(
        const ushort* __restrict__ linS, ushort* __restrict__ h1b,
        const ushort* __restrict__ csr_td, const int* __restrict__ off_td,
        const ushort* __restrict__ deg_td, const float* __restrict__ dinv_td,
        const ushort* __restrict__ csr_bu, const int* __restrict__ off_bu,
        const ushort* __restrict__ deg_bu, const float* __restrict__ dinv_bu,
        const float* __restrict__ b_td, const float* __restrict__ b_bu) {
    int n = blockIdx.x;
    int br = threadIdx.x >> 6, lane = threadIdx.x & 63;
    const ushort* csr = br ? csr_bu : csr_td;
    const int* off    = br ? off_bu : off_td;
    const ushort* deg = br ? deg_bu : deg_td;
    const float* dinv = br ? dinv_bu : dinv_td;
    const float* bias = br ? b_bu : b_td;
    size_t cbase = (size_t)br * F_H + lane * 2;
    const ushort* base = linS + cbase;

    uint v = *(const uint*)(base + (size_t)n * F_CAT);
    float a0 = bflo(v), a1 = bfhi(v);
    int s = off[n];
    gather_row(base, csr, s, s + deg[n], a0, a1);
    float dn = dinv[n];
    float o0 = fmaxf(a0 * dn + bias[lane * 2], 0.f);
    float o1 = fmaxf(a1 * dn + bias[lane * 2 + 1], 0.f);
    uint pk = (uint)f2bf(o0) | ((uint)f2bf(o1) << 16);
    *(uint*)(h1b + (size_t)n * F_CAT + cbase) = pk;
}

// ---------------------------------------------------------------------------
// Layer-2 aggregation fused with global_add_pool. 8 nodes/block; batch sorted,
// per-graph segment accumulate + one atomic flush pair.
__global__ __launch_bounds__(128) void agg2_pool_kernel(
        const ushort* __restrict__ linS, float* __restrict__ pooled,
        const int* __restrict__ batch,
        const ushort* __restrict__ csr_td, const int* __restrict__ off_td,
        const ushort* __restrict__ deg_td, const float* __restrict__ dinv_td,
        const ushort* __restrict__ csr_bu, const int* __restrict__ off_bu,
        const ushort* __restrict__ deg_bu, const float* __restrict__ dinv_bu,
        const float* __restrict__ b_td, const float* __restrict__ b_bu) {
    int n0 = blockIdx.x * 8;
    int br = threadIdx.x >> 6, lane = threadIdx.x & 63;
    const ushort* csr = br ? csr_bu : csr_td;
    const int* off    = br ? off_bu : off_td;
    const ushort* deg = br ? deg_bu : deg_td;
    const float* dinv = br ? dinv_bu : dinv_td;
    const float* bias = br ? b_bu : b_td;
    size_t cbase = (size_t)br * F_H + lane * 2;
    const ushort* base = linS + cbase;
    int pcol = (br ? 0 : F_H) + lane * 2;
    float bs0 = bias[lane * 2], bs1 = bias[lane * 2 + 1];

    float acc0 = 0.f, acc1 = 0.f;
    int gcur = batch[n0];
#pragma unroll
    for (int j = 0; j < 8; j++) {
        int n = n0 + j;
        int g = batch[n];
        if (g != gcur) {  // wave-uniform
            unsafeAtomicAdd(&pooled[(size_t)gcur * F_CAT + pcol], acc0);
            unsafeAtomicAdd(&pooled[(size_t)gcur * F_CAT + pcol + 1], acc1);
            acc0 = acc1 = 0.f;
            gcur = g;
        }
        uint v = *(const uint*)(base + (size_t)n * F_CAT);
        float a0 = bflo(v), a1 = bfhi(v);
        int s = off[n];
        gather_row(base, csr, s, s + deg[n], a0, a1);
        float dn = dinv[n];
        acc0 += a0 * dn + bs0;
        acc1 += a1 * dn + bs1;
    }
    unsafeAtomicAdd(&pooled[(size_t)gcur * F_CAT + pcol], acc0);
    unsafeAtomicAdd(&pooled[(size_t)gcur * F_CAT + pcol + 1], acc1);
}

// ---------------------------------------------------------------------------
__global__ __launch_bounds__(256) void mlp_kernel(const float* __restrict__ pooled,
                                                  const float* __restrict__ pw1,
                                                  const float* __restrict__ pb1,
                                                  const float* __restrict__ pw2,
                                                  const float* __restrict__ pb2,
                                                  float* __restrict__ out) {
    int g = blockIdx.x;
    int tid = threadIdx.x;
    __shared__ float row[256];
    __shared__ float hid[256];
    row[tid] = pooled[(size_t)g * 256 + tid];
    __syncthreads();
    float acc = pb1[tid];
    for (int k = 0; k < 256; k++) acc += row[k] * pw1[(size_t)k * 256 + tid];
    hid[tid] = fmaxf(acc, 0.f);
    __syncthreads();
    if (tid < 128) {
        float o = pb2[tid];
        for (int k = 0; k < 256; k++) o += hid[k] * pw2[(size_t)k * 128 + tid];
        out[(size_t)g * 128 + tid] = o;
    }
}

// ---------------------------------------------------------------------------
extern "C" void kernel_launch(void* const* d_in, const int* in_sizes, int n_in,
                              void* d_out, int out_size, void* d_ws, size_t ws_size,
                              hipStream_t stream) {
    const float* x     = (const float*)d_in[0];
    const int*   ei    = (const int*)d_in[1];
    const int*   batch = (const int*)d_in[2];
    const float* td_W1 = (const float*)d_in[4];
    const float* td_b1 = (const float*)d_in[5];
    const float* td_W2 = (const float*)d_in[6];
    const float* td_b2 = (const float*)d_in[7];
    const float* bu_W1 = (const float*)d_in[8];
    const float* bu_b1 = (const float*)d_in[9];
    const float* bu_W2 = (const float*)d_in[10];
    const float* bu_b2 = (const float*)d_in[11];
    const float* pw1   = (const float*)d_in[12];
    const float* pb1   = (const float*)d_in[13];
    const float* pw2   = (const float*)d_in[14];
    const float* pb2   = (const float*)d_in[15];
    float* out = (float*)d_out;

    // ---- workspace carve ----
    char* p = (char*)d_ws;
    auto alloc = [&](size_t bytes) { void* r = (void*)p; p += (bytes + 255) & ~(size_t)255; return r; };
    int* gcur = (int*)alloc(2 * NB * sizeof(int));
    uint* ebuf_td = (uint*)alloc((size_t)NB * CAP * sizeof(uint));
    uint* ebuf_bu = (uint*)alloc((size_t)NB * CAP * sizeof(uint));
    ushort* csr_td = (ushort*)alloc((size_t)NB * CAP * sizeof(ushort));
    ushort* csr_bu = (ushort*)alloc((size_t)NB * CAP * sizeof(ushort));
    int* off_td = (int*)alloc((size_t)N_NODES * sizeof(int));
    int* off_bu = (int*)alloc((size_t)N_NODES * sizeof(int));
    ushort* deg_td = (ushort*)alloc((size_t)N_NODES * sizeof(ushort));
    ushort* deg_bu = (ushort*)alloc((size_t)N_NODES * sizeof(ushort));
    float* dinv_td = (float*)alloc((size_t)N_PAD * sizeof(float));
    float* dinv_bu = (float*)alloc((size_t)N_PAD * sizeof(float));
    ushort* Bt1 = (ushort*)alloc((size_t)256 * 256 * sizeof(ushort));
    ushort* Bt2 = (ushort*)alloc((size_t)256 * 128 * sizeof(ushort));
    ushort* xb   = (ushort*)alloc((size_t)N_PAD * F_CAT * sizeof(ushort));
    ushort* linb = (ushort*)alloc((size_t)N_PAD * F_CAT * sizeof(ushort));
    ushort* h1b  = (ushort*)alloc((size_t)N_PAD * F_CAT * sizeof(ushort));
    float* pooled = (float*)alloc((size_t)N_GRAPHS * F_CAT * sizeof(float));  // memset

    hipMemsetAsync(pooled, 0, (size_t)N_GRAPHS * F_CAT * sizeof(float), stream);

    // ---- graph structure (bucketed counting sort) ----
    init_gcur_kernel<<<1, 256, 0, stream>>>(gcur);
    csr_scatter_kernel<<<N_EDGES / EPB, 256, 0, stream>>>(ei, gcur, ebuf_td, ebuf_bu);
    csr_build_kernel<<<dim3(NB, 2), 256, 0, stream>>>(ebuf_td, ebuf_bu, gcur,
        off_td, off_bu, deg_td, deg_bu, dinv_td, dinv_bu, csr_td, csr_bu);

    // ---- bf16 conversions ----
    cvt_x_kernel<<<(N_PAD * F_IN / 4) / 256, 256, 0, stream>>>(x, xb);
    prep_w_kernel<<<256, 256, 0, stream>>>(td_W1, bu_W1, td_W2, bu_W2, Bt1, Bt2);

    dim3 gg(N_PAD / 128, 2);

    // ---- layer 1 ----
    gemm_mfma<<<gg, 256, 0, stream>>>(xb, Bt1, linb, dinv_td, dinv_bu, 256, 256, 0);
    agg1_kernel<<<N_NODES, 128, 0, stream>>>(linb, h1b,
        csr_td, off_td, deg_td, dinv_td, csr_bu, off_bu, deg_bu, dinv_bu, td_b1, bu_b1);

    // ---- layer 2 (block-diagonal -> K=128 split) + pool ----
    gemm_mfma<<<gg, 256, 0, stream>>>(h1b, Bt2, linb, dinv_td, dinv_bu, 128, 128, 1);
    agg2_pool_kernel<<<N_NODES / 8, 128, 0, stream>>>(linb, pooled, batch,
        csr_td, off_td, deg_td, dinv_td, csr_bu, off_bu, deg_bu, dinv_bu, td_b2, bu_b2);

    // ---- projection head ----
    mlp_kernel<<<N_GRAPHS, 256, 0, stream>>>(pooled, pw1, pb1, pw2, pb2, out);
}